// Round 1
// baseline (97.392 us; speedup 1.0000x reference)
//
#include <hip/hip_runtime.h>

// InvariantMessagePassingTP: out[n, lm, c] = sum_{e : recv[e]==n}
//     node_feats[send[e], c] * edge_attrs[e, lm] * tp_weights[e, L_MAP[lm], c]
// receiver_list is SORTED; first_occurences[n] = start of node n's edge segment.
// One 128-thread block per node (thread = channel), 16 reg accumulators (lm),
// no atomics. Memory-bound: tp_weights (327.7 MB) read exactly once.

__global__ __launch_bounds__(128)
void impt_kernel(const float* __restrict__ node_feats,
                 const float* __restrict__ edge_attrs,
                 const float* __restrict__ tp_weights,
                 const int*   __restrict__ sender_list,
                 const int*   __restrict__ first_occ,
                 float*       __restrict__ out,
                 int nnodes, int nedges)
{
    const int n = blockIdx.x;
    const int c = threadIdx.x;                 // 0..127 = channel
    const int start = first_occ[n];
    const int end   = (n + 1 < nnodes) ? first_occ[n + 1] : nedges;

    float acc[16];
#pragma unroll
    for (int i = 0; i < 16; ++i) acc[i] = 0.0f;

    for (int e = start; e < end; ++e) {
        const int   s  = sender_list[e];
        const float sf = node_feats[(size_t)s * 128 + c];          // gathered, coalesced over c

        const float* tw = tp_weights + (size_t)e * 512 + c;        // 4 coalesced rows
        const float p0 = sf * tw[0];
        const float p1 = sf * tw[128];
        const float p2 = sf * tw[256];
        const float p3 = sf * tw[384];

        const float4* ea4 = reinterpret_cast<const float4*>(edge_attrs + (size_t)e * 16);
        const float4 ea0 = ea4[0];                                 // broadcast (same addr all lanes)
        const float4 ea1 = ea4[1];
        const float4 ea2 = ea4[2];
        const float4 ea3 = ea4[3];

        // L_MAP = [0, 1,1,1, 2,2,2,2,2, 3,3,3,3,3,3,3]
        acc[0]  = fmaf(p0, ea0.x, acc[0]);
        acc[1]  = fmaf(p1, ea0.y, acc[1]);
        acc[2]  = fmaf(p1, ea0.z, acc[2]);
        acc[3]  = fmaf(p1, ea0.w, acc[3]);
        acc[4]  = fmaf(p2, ea1.x, acc[4]);
        acc[5]  = fmaf(p2, ea1.y, acc[5]);
        acc[6]  = fmaf(p2, ea1.z, acc[6]);
        acc[7]  = fmaf(p2, ea1.w, acc[7]);
        acc[8]  = fmaf(p2, ea2.x, acc[8]);
        acc[9]  = fmaf(p3, ea2.y, acc[9]);
        acc[10] = fmaf(p3, ea2.z, acc[10]);
        acc[11] = fmaf(p3, ea2.w, acc[11]);
        acc[12] = fmaf(p3, ea3.x, acc[12]);
        acc[13] = fmaf(p3, ea3.y, acc[13]);
        acc[14] = fmaf(p3, ea3.z, acc[14]);
        acc[15] = fmaf(p3, ea3.w, acc[15]);
    }

    float* o = out + (size_t)n * 2048 + c;
#pragma unroll
    for (int lm = 0; lm < 16; ++lm) o[lm * 128] = acc[lm];         // coalesced stores (zeros if no edges)
}

extern "C" void kernel_launch(void* const* d_in, const int* in_sizes, int n_in,
                              void* d_out, int out_size, void* d_ws, size_t ws_size,
                              hipStream_t stream)
{
    const float* node_feats = (const float*)d_in[0];
    const float* edge_attrs = (const float*)d_in[1];
    const float* tp_weights = (const float*)d_in[2];
    const int*   sender_list = (const int*)d_in[3];
    // d_in[4] = receiver_list (unused; first_occurences encodes the segments)
    const int*   first_occ  = (const int*)d_in[5];

    const int nnodes = in_sizes[5];          // 10000
    const int nedges = in_sizes[3];          // 160000

    impt_kernel<<<nnodes, 128, 0, stream>>>(node_feats, edge_attrs, tp_weights,
                                            sender_list, first_occ,
                                            (float*)d_out, nnodes, nedges);
}